// Round 8
// baseline (98.766 us; speedup 1.0000x reference)
//
#include <hip/hip_runtime.h>
#include <math.h>

// Problem constants: R=4, I=16, N=2048.
#define RDIM 4
#define IDIM 16
#define NPAIR 64
#define NPTS 2048
#define THREADS 256
#define ROWSB 256                   // rows per block (64 per wave)
#define RBLK (NPTS / ROWSB)         // 8
#define TILES (NPTS / 32)           // 64 col-tiles of 32
// Scratch row stride (floats). Multiple of 4 so rows stay 16B-aligned for b128.
#define SCRS 68
#define ONEBF 0x3F80u               // bf16(1.0)

typedef __attribute__((ext_vector_type(8))) short bf16x8;
typedef __attribute__((ext_vector_type(16))) float f32x16;
typedef __attribute__((ext_vector_type(4))) float f32x4;

// NOTE: no inline-asm min3. fminf(a, fminf(b, c)) is pattern-matched by the
// backend into v_min3_f32 with correct MFMA-read hazard handling. The R5/R6
// failures tracked to the raw `asm(v_min3_f32)` reading MFMA results
// (scheduling-sensitive corruption: absmax differed between otherwise
// identical builds).

__device__ __forceinline__ unsigned int f2bf(float f) {
    union { float f; unsigned int u; } v; v.f = f;
    return (v.u + 0x7FFFu + ((v.u >> 16) & 1u)) >> 16;   // RNE bf16 (low 16 bits)
}
__device__ __forceinline__ float bf2f(unsigned int h) {
    union { unsigned int u; float f; } v; v.u = h << 16; return v.f;
}

__device__ __forceinline__ void make_rot(const float* __restrict__ rotv, int pair,
                                         float& r00, float& r01, float& r02,
                                         float& r10, float& r11, float& r12,
                                         float& r20, float& r21, float& r22) {
    const float ax = rotv[pair * 3 + 0];
    const float ay = rotv[pair * 3 + 1];
    const float az = rotv[pair * 3 + 2];
    float sx, cx, sy, cy, sz, cz;
    sincosf(ax, &sx, &cx);
    sincosf(ay, &sy, &cy);
    sincosf(az, &sz, &cz);
    r00 = cy * cz;                r01 = -cy * sz;               r02 = sy;
    r10 = cx * sz + sx * sy * cz; r11 = cx * cz - sx * sy * sz; r12 = -sx * cy;
    r20 = sx * sz - cx * sy * cz; r21 = sx * cz + cx * sy * sz; r22 = cx * cy;
}

// B-record (16 B, identical content consumed by both MFMA k-halves):
//   shorts [bh0,bh1,bh2, bl0,bl1,bl2, n2h, n2l],  b = split(-2v), n2 = |v|^2
__device__ __forceinline__ uint4 brec(float v0, float v1, float v2) {
    const float b0 = -2.0f * v0, b1 = -2.0f * v1, b2 = -2.0f * v2;
    const unsigned int h0 = f2bf(b0), h1 = f2bf(b1), h2 = f2bf(b2);
    const unsigned int l0 = f2bf(b0 - bf2f(h0));
    const unsigned int l1 = f2bf(b1 - bf2f(h1));
    const unsigned int l2 = f2bf(b2 - bf2f(h2));
    const float n2 = v0 * v0 + v1 * v1 + v2 * v2;
    const unsigned int nh = f2bf(n2), nl = f2bf(n2 - bf2f(nh));
    return make_uint4(h0 | (h1 << 16), h2 | (l0 << 16), l1 | (l2 << 16), nh | (nl << 16));
}

// K0: B-records only. blocks 0..63: transformed source -> Yb; 64..79: target -> Xb.
__global__ __launch_bounds__(THREADS)
void prep(const float* __restrict__ src, const float* __restrict__ tgt,
          const float* __restrict__ rotv, const float* __restrict__ trav,
          const float* __restrict__ scal,
          uint4* __restrict__ Yb, uint4* __restrict__ Xb)
{
    const int b = blockIdx.x;
    const int tid = threadIdx.x;
    if (b < NPAIR) {
        const int pair = b;
        float r00, r01, r02, r10, r11, r12, r20, r21, r22;
        make_rot(rotv, pair, r00, r01, r02, r10, r11, r12, r20, r21, r22);
        const float t0 = trav[pair * 3 + 0];
        const float t1 = trav[pair * 3 + 1];
        const float t2 = trav[pair * 3 + 2];
        const float s  = scal[pair];
        const float* __restrict__ srcp = src + (size_t)pair * NPTS * 3;
#pragma unroll
        for (int u = 0; u < NPTS / THREADS; ++u) {
            const int m = u * THREADS + tid;
            const float p0 = srcp[m * 3 + 0];
            const float p1 = srcp[m * 3 + 1];
            const float p2 = srcp[m * 3 + 2];
            const float y0 = s * fmaf(r00, p0, fmaf(r01, p1, fmaf(r02, p2, t0)));
            const float y1 = s * fmaf(r10, p0, fmaf(r11, p1, fmaf(r12, p2, t1)));
            const float y2 = s * fmaf(r20, p0, fmaf(r21, p1, fmaf(r22, p2, t2)));
            Yb[(size_t)pair * NPTS + m] = brec(y0, y1, y2);
        }
    } else {
        const int i = b - NPAIR;
        const float* __restrict__ tgtp = tgt + (size_t)i * NPTS * 3;
#pragma unroll
        for (int u = 0; u < NPTS / THREADS; ++u) {
            const int m = u * THREADS + tid;
            Xb[(size_t)i * NPTS + m] = brec(tgtp[m * 3 + 0], tgtp[m * 3 + 1], tgtp[m * 3 + 2]);
        }
    }
}

// K1: per (pair, rowblock, pass). Wave owns 64 rows x all 2048 cols.
// 32x32x16 MFMA (split-bf16 exact); compiler-formed v_min3 folds 2 tiles/fold;
// A-records computed in-register (1 point/thread), B-records staged from ws.
__global__ __launch_bounds__(THREADS, 3)
void chamfer_main(const float* __restrict__ src, const float* __restrict__ tgt,
                  const float* __restrict__ rotv, const float* __restrict__ trav,
                  const float* __restrict__ scal,
                  const uint4* __restrict__ Yb, const uint4* __restrict__ Xb,
                  float* __restrict__ out)
{
    // [0, 34816): sB 32 KB (loop) / scratch 34816 B (endgame overlay, 4*32*68*4)
    // [34816, 43008): sA 8 KB (A-records, both phases)
    __shared__ alignas(16) unsigned char smem[34816 + 8192];
    __shared__ float rowq2[ROWSB];
    __shared__ float wsum[4];
    unsigned short* sB = (unsigned short*)smem;           // [2048][8] shorts
    float* scratch = (float*)smem;                        // [4][32][SCRS]
    unsigned short* sA = (unsigned short*)(smem + 34816); // [256][16] shorts

    const int pair  = blockIdx.x;
    const int rb    = blockIdx.y;
    const int passB = blockIdx.z;  // 0: rows=target, cols=transformed; 1: swapped
    const int i     = pair & (IDIM - 1);
    const int tid   = threadIdx.x;
    const int lane  = tid & 63;
    const int w     = tid >> 6;
    const int c31   = lane & 31;
    const int h     = lane >> 5;

    // ---- stage sB: all 2048 col records (8 uint4/thread, coalesced) ----
    const uint4* __restrict__ gB = (passB == 0) ? (Yb + (size_t)pair * NPTS)
                                                : (Xb + (size_t)i * NPTS);
#pragma unroll
    for (int j = 0; j < 8; ++j)
        ((uint4*)sB)[j * THREADS + tid] = gB[j * THREADS + tid];

    // ---- A-record for this thread's row, computed in-register ----
    {
        const int n = rb * ROWSB + tid;
        float q0, q1, q2v;
        if (passB == 0) {
            const float* __restrict__ tgtp = tgt + (size_t)i * NPTS * 3;
            q0 = tgtp[n * 3 + 0]; q1 = tgtp[n * 3 + 1]; q2v = tgtp[n * 3 + 2];
        } else {
            float r00, r01, r02, r10, r11, r12, r20, r21, r22;
            make_rot(rotv, pair, r00, r01, r02, r10, r11, r12, r20, r21, r22);
            const float t0 = trav[pair * 3 + 0];
            const float t1 = trav[pair * 3 + 1];
            const float t2 = trav[pair * 3 + 2];
            const float s  = scal[pair];
            const float* __restrict__ srcp = src + (size_t)pair * NPTS * 3;
            const float p0 = srcp[n * 3 + 0];
            const float p1 = srcp[n * 3 + 1];
            const float p2 = srcp[n * 3 + 2];
            q0  = s * fmaf(r00, p0, fmaf(r01, p1, fmaf(r02, p2, t0)));
            q1  = s * fmaf(r10, p0, fmaf(r11, p1, fmaf(r12, p2, t1)));
            q2v = s * fmaf(r20, p0, fmaf(r21, p1, fmaf(r22, p2, t2)));
        }
        rowq2[tid] = q0 * q0 + q1 * q1 + q2v * q2v;   // exact fp32
        const unsigned int h0 = f2bf(q0), h1 = f2bf(q1), h2 = f2bf(q2v);
        const unsigned int l0 = f2bf(q0 - bf2f(h0));
        const unsigned int l1 = f2bf(q1 - bf2f(h1));
        const unsigned int l2 = f2bf(q2v - bf2f(h2));
        uint4* rk = (uint4*)&sA[tid * 16];
        // half0: [qh0,qh1,qh2, ql0,ql1,ql2, 1, 0]  half1: [ql0,ql1,ql2, qh0,qh1,qh2, 0, 1]
        rk[0] = make_uint4(h0 | (h1 << 16), h2 | (l0 << 16), l1 | (l2 << 16), ONEBF);
        rk[1] = make_uint4(l0 | (l1 << 16), l2 | (h0 << 16), h1 | (h2 << 16), ONEBF << 16);
    }
    __syncthreads();

    // ---- A fragments: wave w's rows, 2 row-tiles of 32 ----
    bf16x8 af0 = *(const bf16x8*)&sA[(w * 64 + c31) * 16 + h * 8];
    bf16x8 af1 = *(const bf16x8*)&sA[(w * 64 + 32 + c31) * 16 + h * 8];

    float mn0[16], mn1[16];
#pragma unroll
    for (int j = 0; j < 16; ++j) { mn0[j] = 3.4e38f; mn1[j] = 3.4e38f; }

    const f32x16 zero16 = {0,0,0,0, 0,0,0,0, 0,0,0,0, 0,0,0,0};

    // ---- main loop: 2 tiles per step; fminf(fminf(..)) -> compiler v_min3 ----
#pragma unroll 2
    for (int t2 = 0; t2 < TILES / 2; ++t2) {
        const bf16x8 bfA = *(const bf16x8*)&sB[((t2 * 2 + 0) * 32 + c31) * 8];
        const bf16x8 bfB = *(const bf16x8*)&sB[((t2 * 2 + 1) * 32 + c31) * 8];
        const f32x16 d0a = __builtin_amdgcn_mfma_f32_32x32x16_bf16(af0, bfA, zero16, 0, 0, 0);
        const f32x16 d0b = __builtin_amdgcn_mfma_f32_32x32x16_bf16(af0, bfB, zero16, 0, 0, 0);
#pragma unroll
        for (int j = 0; j < 16; ++j)
            mn0[j] = fminf(mn0[j], fminf(d0a[j], d0b[j]));
        const f32x16 d1a = __builtin_amdgcn_mfma_f32_32x32x16_bf16(af1, bfA, zero16, 0, 0, 0);
        const f32x16 d1b = __builtin_amdgcn_mfma_f32_32x32x16_bf16(af1, bfB, zero16, 0, 0, 0);
#pragma unroll
        for (int j = 0; j < 16; ++j)
            mn1[j] = fminf(mn1[j], fminf(d1a[j], d1b[j]));
    }
    __syncthreads();   // done with sB; scratch overlays it

    // ---- endgame: LDS transpose. reg j of tile rt -> local row rt*32+8*(j>>2)+4*h+(j&3) ----
#pragma unroll
    for (int g2 = 0; g2 < 4; ++g2) {
        f32x4 v4;
        v4[0] = mn0[g2 * 4 + 0]; v4[1] = mn0[g2 * 4 + 1];
        v4[2] = mn0[g2 * 4 + 2]; v4[3] = mn0[g2 * 4 + 3];
        *(f32x4*)&scratch[(w * 32 + c31) * SCRS + 8 * g2 + 4 * h] = v4;
        v4[0] = mn1[g2 * 4 + 0]; v4[1] = mn1[g2 * 4 + 1];
        v4[2] = mn1[g2 * 4 + 2]; v4[3] = mn1[g2 * 4 + 3];
        *(f32x4*)&scratch[(w * 32 + c31) * SCRS + 32 + 8 * g2 + 4 * h] = v4;
    }
    __syncthreads();

    // ---- thread tid = block-row tid: min over 32 col-classes + |q|^2, block-sum ----
    float m = scratch[(w * 32) * SCRS + lane];
#pragma unroll
    for (int c = 1; c < 32; ++c)
        m = fminf(m, scratch[(w * 32 + c) * SCRS + lane]);
    float v = m + rowq2[tid];

#pragma unroll
    for (int off = 32; off > 0; off >>= 1)
        v += __shfl_down(v, off, 64);
    if (lane == 0) wsum[w] = v;
    __syncthreads();
    if (tid == 0) {
        const float tot = wsum[0] + wsum[1] + wsum[2] + wsum[3];
        atomicAdd(&out[pair], tot * (1.0f / NPTS));
    }
}

extern "C" void kernel_launch(void* const* d_in, const int* in_sizes, int n_in,
                              void* d_out, int out_size, void* d_ws, size_t ws_size,
                              hipStream_t stream) {
    const float* src  = (const float*)d_in[0];  // [4,16,2048,3]
    const float* tgt  = (const float*)d_in[1];  // [16,2048,3]
    const float* rotv = (const float*)d_in[2];  // [4,16,3]
    const float* trav = (const float*)d_in[3];  // [4,16,3]
    const float* scal = (const float*)d_in[4];  // [4,16]
    float* out = (float*)d_out;                 // [4,16]

    // ws: Yb 2 MB | Xb 0.5 MB
    char* ws = (char*)d_ws;
    uint4* Yb = (uint4*)ws;
    uint4* Xb = (uint4*)(ws + (size_t)NPAIR * NPTS * 16);

    hipMemsetAsync(out, 0, NPAIR * sizeof(float), stream);

    prep<<<NPAIR + IDIM, THREADS, 0, stream>>>(src, tgt, rotv, trav, scal, Yb, Xb);

    dim3 grid(NPAIR, RBLK, 2);
    chamfer_main<<<grid, THREADS, 0, stream>>>(src, tgt, rotv, trav, scal, Yb, Xb, out);
}